// Round 18
// baseline (73.902 us; speedup 1.0000x reference)
//
#include <hip/hip_runtime.h>

// Problem constants (from reference)
#define NNODES 10000
#define DDEG   64
#define NEDGES 32768
#define FIN    64
#define HID    256

typedef __attribute__((ext_vector_type(8))) __bf16 bf16x8;
typedef __attribute__((ext_vector_type(4))) float  f32x4;

__device__ __forceinline__ unsigned short f2bf(float f) {
    unsigned x = __float_as_uint(f);
    return (unsigned short)((x + 0x7FFFu + ((x >> 16) & 1u)) >> 16);  // RNE
}
__device__ __forceinline__ float b2f(unsigned short u) {
    return __uint_as_float(((unsigned)u) << 16);
}

// Blocked transposed-weight layout (bf16): WT[k>>5][n][k&31], tile = 8192 elems (16KB).
// Within a tile, col c's 32-k slice (64B) is contiguous; a wave's 16-col B-load is
// 1KB fully coalesced.
#define OFF_XIJ1 0        // K=64  : tiles 0..1
#define OFF_XIJ2 16384    // K=256 : tiles 2..9
#define OFF_XCN1 81920    // tiles 10..11
#define OFF_XCN2 98304    // tiles 12..19
#define OFF_XCN3 163840   // tiles 20..27
#define OFF_LIN1 229376   // tiles 28..35
#define WT_TOTAL 294912
#define NTILES   36

__host__ __device__ constexpr int tile_off(int t) {
    return t < 2  ? OFF_XIJ1 + t * 8192
         : t < 10 ? OFF_XIJ2 + (t - 2) * 8192
         : t < 12 ? OFF_XCN1 + (t - 10) * 8192
         : t < 20 ? OFF_XCN2 + (t - 12) * 8192
         : t < 28 ? OFF_XCN3 + (t - 20) * 8192
         :          OFF_LIN1 + (t - 28) * 8192;
}

// ---- async global->LDS (LDS dest = wave-uniform base + lane*16B) ----
__device__ __forceinline__ void gll16(const unsigned short* g, unsigned short* l) {
    __builtin_amdgcn_global_load_lds(
        (const __attribute__((address_space(1))) unsigned int*)g,
        (__attribute__((address_space(3))) unsigned int*)l, 16, 0, 0);
}
// 16KB activation tile (128x64 bf16) with 256 threads: 4 gll16/thread
__device__ __forceinline__ void stage_act16(const unsigned short* g, unsigned short* l,
                                            int tid, int wv) {
#pragma unroll
    for (int c = 0; c < 4; ++c)
        gll16(g + c * 2048 + tid * 8, l + c * 2048 + wv * 512);
}

// Edge stage (1 edge per wave, latency TLP-hidden at 8192 blocks) + weight-prep piggyback.
// xij/xcn written PRE-SWIZZLED (elem ^= (row&7)<<3) so linear global_load_lds staging
// lands in the swizzled layout the mlp A-fragment ds_reads expect.
__global__ __launch_bounds__(256) void edge_prep_k(const float* __restrict__ x,
                                                   const int* __restrict__ adj,
                                                   const int* __restrict__ tar,
                                                   const float* __restrict__ xij_w1,
                                                   const float* __restrict__ xij_w2,
                                                   const float* __restrict__ xcn_w1,
                                                   const float* __restrict__ xcn_w2,
                                                   const float* __restrict__ xcn_w3,
                                                   const float* __restrict__ lin_w1,
                                                   unsigned short* __restrict__ WT,
                                                   unsigned short* __restrict__ xij_g,
                                                   unsigned short* __restrict__ xcn_g) {
    const int wv   = threadIdx.x >> 6;
    const int lane = threadIdx.x & 63;
    const int e    = blockIdx.x * 4 + wv;      // grid = NEDGES/4 = 8192

    int i = tar[e];
    int j = tar[NEDGES + e];
    int ni = adj[i * DDEG + lane];
    int nj = adj[j * DDEG + lane];
    float xi = x[i * FIN + lane];
    float xj = x[j * FIN + lane];

    bool found = false;
#pragma unroll
    for (int b = 0; b < 64; ++b)
        found |= (ni == (int)__builtin_amdgcn_readlane(nj, b));
    unsigned long long m = __ballot(found);

    float acc = 0.f;
    while (m) {
        int a = __ffsll(m) - 1;
        m &= m - 1;
        int r = (int)__builtin_amdgcn_readlane(ni, a);
        acc += x[r * FIN + lane];
    }
    int sl = lane ^ ((e & 7) << 3);            // pre-swizzle (row&7 == e&7)
    xij_g[(size_t)e * FIN + sl] = f2bf(xi * xj);
    xcn_g[(size_t)e * FIN + sl] = f2bf(acc);

    // ---- weight-prep piggyback: fp32 W[K,256] -> blocked bf16 WT ----
    if (blockIdx.x < WT_TOTAL / 256) {
        int idx = blockIdx.x * 256 + threadIdx.x;
        const float* src;
        int r;
        if (idx < OFF_XIJ2)      { r = idx - OFF_XIJ1; src = xij_w1; }
        else if (idx < OFF_XCN1) { r = idx - OFF_XIJ2; src = xij_w2; }
        else if (idx < OFF_XCN2) { r = idx - OFF_XCN1; src = xcn_w1; }
        else if (idx < OFF_XCN3) { r = idx - OFF_XCN2; src = xcn_w2; }
        else if (idx < OFF_LIN1) { r = idx - OFF_XCN3; src = xcn_w3; }
        else                     { r = idx - OFF_LIN1; src = lin_w1; }
        int kb  = r >> 13;
        int n   = (r & 8191) >> 5;
        int klo = r & 31;
        WT[idx] = f2bf(src[(kb * 32 + klo) * HID + n]);
    }
}

// BARRIER-FREE k-loop phase; m8n4 per wave (all 128 rows x 64-col slice); B in a
// 4-slot REGISTER rotation bq[t&3][4]. Tile t's 4 coalesced 1KB loads were issued
// at the END of step t-4 (~3 steps of slack). Per step:
//   ds_read a[8] (shared As, read-only) ; 32 MFMA on bq[t&3] ; issue loads for
//   tile t+4 into bq[(t+4)&3] — the slot just consumed, so register WAR pins the
//   issue AFTER the MFMAs. No LDS writes for B, no in-loop barriers.
template <int T0, int NT, int LDA>
__device__ __forceinline__ void run_phase(const unsigned short* As,
                                          const unsigned short* __restrict__ WT,
                                          int boff, int lr, int lg,
                                          bf16x8 (&bq)[4][4], f32x4 acc[8][4]) {
#pragma unroll
    for (int mm = 0; mm < 8; ++mm)
#pragma unroll
        for (int n = 0; n < 4; ++n) acc[mm][n] = (f32x4){0.f, 0.f, 0.f, 0.f};
    const int sw = (lr & 7) << 3;
#pragma unroll
    for (int s = 0; s < NT; ++s) {
        const int t = T0 + s;
        bf16x8 a[8];
#pragma unroll
        for (int mm = 0; mm < 8; ++mm)
            a[mm] = *reinterpret_cast<const bf16x8*>(
                &As[(mm * 16 + lr) * LDA + ((s * 32 + 8 * lg) ^ sw)]);
        __builtin_amdgcn_s_setprio(1);
#pragma unroll
        for (int mm = 0; mm < 8; ++mm)
#pragma unroll
            for (int n = 0; n < 4; ++n)
                acc[mm][n] = __builtin_amdgcn_mfma_f32_16x16x32_bf16(a[mm], bq[t & 3][n], acc[mm][n], 0, 0, 0);
        __builtin_amdgcn_s_setprio(0);
        if (t + 4 < NTILES) {
#pragma unroll
            for (int n = 0; n < 4; ++n)
                bq[(t + 4) & 3][n] = *reinterpret_cast<const bf16x8*>(
                    &WT[tile_off(t + 4) + boff + n * 512]);
        }
    }
}

__device__ __forceinline__ void fence_barrier() {
    asm volatile("s_waitcnt lgkmcnt(0)" ::: "memory");   // own ds ops drained
    __builtin_amdgcn_s_barrier();                        // global loads stay in flight
}

// MLP over 128-edge tiles; 4 waves (256 thr); grid 256 = exactly ONE block/CU and
// ONE 36-step pass/CU (steps/CU halved vs 64-edge tiling; B L2 traffic halved).
// Wave wv: ALL 128 rows, cols wv*64..+64 (m8n4). __launch_bounds__(256,1): 1 block
// -> 1 wave/SIMD -> VGPR cap 512: acc(128)+bq(64)+hij(64)+a(32) fit, no spill,
// hij stays in registers. LDS 96 KB (16 sXij + 16 sXcn + 64 sH).
// D-frag lane l: row = mm*16 + 4*(l>>4) + i, col = col0 + n*16 + (l&15).
__global__ __launch_bounds__(256, 1) void mlp_k(const unsigned short* __restrict__ xij_g,
                                                const unsigned short* __restrict__ xcn_g,
                                                const unsigned short* __restrict__ WT,
                                                const float* __restrict__ xij_b1,
                                                const float* __restrict__ xij_b2,
                                                const float* __restrict__ xcn_b1,
                                                const float* __restrict__ xcn_b2,
                                                const float* __restrict__ xcn_b3,
                                                const float* __restrict__ lin_b1,
                                                const float* __restrict__ lin_w2,
                                                const float* __restrict__ lin_b2,
                                                const float* __restrict__ beta,
                                                float* __restrict__ out) {
    __shared__ unsigned short sXij[128 * 64];   // 16 KB, pre-swizzled (sRed alias later)
    __shared__ unsigned short sXcn[128 * 64];   // 16 KB, pre-swizzled
    __shared__ unsigned short sH[128 * 256];    // 64 KB activation (in-place reuse)

    const int tid  = threadIdx.x;
    const int wv   = tid >> 6;
    const int lane = tid & 63;
    const int lr   = lane & 15;
    const int lg   = lane >> 4;
    const int col0 = wv * 64;
    const int row0 = blockIdx.x * 128;
    const int boff = (col0 + lr) * 32 + 8 * lg;   // wave's B-slice offset within a tile

    // prologue: stage sXij+sXcn (8 gll16/wave), preload B tiles 0..3 (16 loads).
    // vmcnt(16) completes the 8 gll16 (FIFO); bq loads auto-waited at first MFMA use.
    stage_act16(xij_g + (size_t)row0 * FIN, sXij, tid, wv);
    stage_act16(xcn_g + (size_t)row0 * FIN, sXcn, tid, wv);
    bf16x8 bq[4][4];
#pragma unroll
    for (int t = 0; t < 4; ++t)
#pragma unroll
        for (int n = 0; n < 4; ++n)
            bq[t][n] = *reinterpret_cast<const bf16x8*>(&WT[tile_off(t) + boff + n * 512]);
    const float betaf = beta[0];
    asm volatile("s_waitcnt vmcnt(16)" ::: "memory");
    __builtin_amdgcn_s_barrier();

    f32x4 acc[8][4];
    float bl[4];

    // ---- P1 (t=0,1): h1 = relu(xij @ xij_w1 + b1) -> sH ----
    run_phase<0, 2, 64>(sXij, WT, boff, lr, lg, bq, acc);
#pragma unroll
    for (int n = 0; n < 4; ++n) bl[n] = xij_b1[col0 + n * 16 + lr];
#pragma unroll
    for (int mm = 0; mm < 8; ++mm)
#pragma unroll
        for (int n = 0; n < 4; ++n)
#pragma unroll
            for (int i = 0; i < 4; ++i) {
                int row = mm * 16 + 4 * lg + i;
                int col = col0 + n * 16 + lr;
                sH[row * HID + (col ^ ((row & 7) << 3))] = f2bf(fmaxf(acc[mm][n][i] + bl[n], 0.f));
            }
    fence_barrier();   // B1: sH(h1) visible to all waves

    // ---- P2 (t=2..9): h_ij = h1 @ xij_w2 + b2 -> registers (packed bf16, 64 VGPR) ----
    run_phase<2, 8, 256>(sH, WT, boff, lr, lg, bq, acc);
#pragma unroll
    for (int n = 0; n < 4; ++n) bl[n] = xij_b2[col0 + n * 16 + lr];
    unsigned hij_lo[8][4], hij_hi[8][4];
#pragma unroll
    for (int mm = 0; mm < 8; ++mm)
#pragma unroll
        for (int n = 0; n < 4; ++n) {
            hij_lo[mm][n] = ((unsigned)f2bf(acc[mm][n][1] + bl[n]) << 16) | f2bf(acc[mm][n][0] + bl[n]);
            hij_hi[mm][n] = ((unsigned)f2bf(acc[mm][n][3] + bl[n]) << 16) | f2bf(acc[mm][n][2] + bl[n]);
        }
    fence_barrier();   // B2: all waves' sH(h1) reads done; P3 epi may overwrite sH

    // ---- P3 (t=10,11): t1 = relu(xcn @ xcn_w1 + b1) -> sH ----
    run_phase<10, 2, 64>(sXcn, WT, boff, lr, lg, bq, acc);
#pragma unroll
    for (int n = 0; n < 4; ++n) bl[n] = xcn_b1[col0 + n * 16 + lr];
#pragma unroll
    for (int mm = 0; mm < 8; ++mm)
#pragma unroll
        for (int n = 0; n < 4; ++n)
#pragma unroll
            for (int i = 0; i < 4; ++i) {
                int row = mm * 16 + 4 * lg + i;
                int col = col0 + n * 16 + lr;
                sH[row * HID + (col ^ ((row & 7) << 3))] = f2bf(fmaxf(acc[mm][n][i] + bl[n], 0.f));
            }
    fence_barrier();   // B3: sH(t1) visible

    // ---- P4 (t=12..19): t2 = relu(t1 @ xcn_w2 + b2) -> sH IN PLACE ----
    run_phase<12, 8, 256>(sH, WT, boff, lr, lg, bq, acc);
    fence_barrier();   // B4: all waves' t1 reads done before overwrite
#pragma unroll
    for (int n = 0; n < 4; ++n) bl[n] = xcn_b2[col0 + n * 16 + lr];
#pragma unroll
    for (int mm = 0; mm < 8; ++mm)
#pragma unroll
        for (int n = 0; n < 4; ++n)
#pragma unroll
            for (int i = 0; i < 4; ++i) {
                int row = mm * 16 + 4 * lg + i;
                int col = col0 + n * 16 + lr;
                sH[row * HID + (col ^ ((row & 7) << 3))] = f2bf(fmaxf(acc[mm][n][i] + bl[n], 0.f));
            }
    fence_barrier();   // B5: sH(t2) visible

    // ---- P5 (t=20..27): u = (t2 @ xcn_w3 + b3) * beta + h_ij -> sH IN PLACE ----
    run_phase<20, 8, 256>(sH, WT, boff, lr, lg, bq, acc);
    fence_barrier();   // B6: all waves' t2 reads done
#pragma unroll
    for (int n = 0; n < 4; ++n) bl[n] = xcn_b3[col0 + n * 16 + lr];
#pragma unroll
    for (int mm = 0; mm < 8; ++mm)
#pragma unroll
        for (int n = 0; n < 4; ++n) {
            float h0 = b2f((unsigned short)(hij_lo[mm][n] & 0xFFFF));
            float h1 = b2f((unsigned short)(hij_lo[mm][n] >> 16));
            float h2 = b2f((unsigned short)(hij_hi[mm][n] & 0xFFFF));
            float h3 = b2f((unsigned short)(hij_hi[mm][n] >> 16));
            float v0 = (acc[mm][n][0] + bl[n]) * betaf + h0;
            float v1 = (acc[mm][n][1] + bl[n]) * betaf + h1;
            float v2 = (acc[mm][n][2] + bl[n]) * betaf + h2;
            float v3 = (acc[mm][n][3] + bl[n]) * betaf + h3;
            int rb = mm * 16 + 4 * lg;
            int col = col0 + n * 16 + lr;
            sH[(rb + 0) * HID + (col ^ (((rb + 0) & 7) << 3))] = f2bf(v0);
            sH[(rb + 1) * HID + (col ^ (((rb + 1) & 7) << 3))] = f2bf(v1);
            sH[(rb + 2) * HID + (col ^ (((rb + 2) & 7) << 3))] = f2bf(v2);
            sH[(rb + 3) * HID + (col ^ (((rb + 3) & 7) << 3))] = f2bf(v3);
        }
    fence_barrier();   // B7: sH(u) visible

    // ---- P6 (t=28..35): out = relu(u @ lin_w1 + lb1) . lin_w2 + lb2 ----
    run_phase<28, 8, 256>(sH, WT, boff, lr, lg, bq, acc);
#pragma unroll
    for (int n = 0; n < 4; ++n) bl[n] = lin_b1[col0 + n * 16 + lr];
    float w2l[4];
#pragma unroll
    for (int n = 0; n < 4; ++n) w2l[n] = lin_w2[col0 + n * 16 + lr];
    float* sRed = (float*)sXij;   // sXij dead since P1; 4 col-groups x 128 rows f32 (2 KB)
#pragma unroll
    for (int mm = 0; mm < 8; ++mm) {
        float p[4] = {0.f, 0.f, 0.f, 0.f};
#pragma unroll
        for (int n = 0; n < 4; ++n)
#pragma unroll
            for (int i = 0; i < 4; ++i)
                p[i] += fmaxf(acc[mm][n][i] + bl[n], 0.f) * w2l[n];
#pragma unroll
        for (int i = 0; i < 4; ++i) {
            float s = p[i];
            s += __shfl_xor(s, 1);
            s += __shfl_xor(s, 2);
            s += __shfl_xor(s, 4);
            s += __shfl_xor(s, 8);
            if (lr == 0) sRed[wv * 128 + mm * 16 + 4 * lg + i] = s;
        }
    }
    __syncthreads();
    if (tid < 128)
        out[row0 + tid] = sRed[tid] + sRed[128 + tid] + sRed[256 + tid] + sRed[384 + tid] + lin_b2[0];
}

extern "C" void kernel_launch(void* const* d_in, const int* in_sizes, int n_in,
                              void* d_out, int out_size, void* d_ws, size_t ws_size,
                              hipStream_t stream) {
    const float* x      = (const float*)d_in[0];
    const int*   adj    = (const int*)d_in[1];
    const int*   tar    = (const int*)d_in[2];
    const float* beta   = (const float*)d_in[3];
    const float* xcn_w1 = (const float*)d_in[4];
    const float* xcn_b1 = (const float*)d_in[5];
    const float* xcn_w2 = (const float*)d_in[6];
    const float* xcn_b2 = (const float*)d_in[7];
    const float* xcn_w3 = (const float*)d_in[8];
    const float* xcn_b3 = (const float*)d_in[9];
    const float* xij_w1 = (const float*)d_in[10];
    const float* xij_b1 = (const float*)d_in[11];
    const float* xij_w2 = (const float*)d_in[12];
    const float* xij_b2 = (const float*)d_in[13];
    const float* lin_w1 = (const float*)d_in[14];
    const float* lin_b1 = (const float*)d_in[15];
    const float* lin_w2 = (const float*)d_in[16];
    const float* lin_b2 = (const float*)d_in[17];

    unsigned short* WT    = (unsigned short*)d_ws;                     // 576 KiB
    unsigned short* xij_g = (unsigned short*)((char*)d_ws + 589824);   // 4 MiB
    unsigned short* xcn_g = (unsigned short*)((char*)d_ws + 4784128);  // 4 MiB

    edge_prep_k<<<NEDGES / 4, 256, 0, stream>>>(x, adj, tar,
                                                xij_w1, xij_w2, xcn_w1, xcn_w2, xcn_w3, lin_w1,
                                                WT, xij_g, xcn_g);
    mlp_k<<<NEDGES / 128, 256, 0, stream>>>(xij_g, xcn_g, WT,
                                            xij_b1, xij_b2, xcn_b1, xcn_b2, xcn_b3,
                                            lin_b1, lin_w2, lin_b2, beta, (float*)d_out);
}

// Round 19
// 69.713 us; speedup vs baseline: 1.0601x; 1.0601x over previous
//
#include <hip/hip_runtime.h>

// Problem constants (from reference)
#define NNODES 10000
#define DDEG   64
#define NEDGES 32768
#define FIN    64
#define HID    256

typedef __attribute__((ext_vector_type(8))) __bf16 bf16x8;
typedef __attribute__((ext_vector_type(4))) float  f32x4;

__device__ __forceinline__ unsigned short f2bf(float f) {
    unsigned x = __float_as_uint(f);
    return (unsigned short)((x + 0x7FFFu + ((x >> 16) & 1u)) >> 16);  // RNE
}
__device__ __forceinline__ float b2f(unsigned short u) {
    return __uint_as_float(((unsigned)u) << 16);
}

// Blocked transposed-weight layout (bf16): WT[k>>5][n][k&31], tile = 8192 elems (16KB).
// Within a tile, col c's 32-k slice (64B) is contiguous; a wave's 16-col B-load is
// 1KB fully coalesced.
#define OFF_XIJ1 0        // K=64  : tiles 0..1
#define OFF_XIJ2 16384    // K=256 : tiles 2..9
#define OFF_XCN1 81920    // tiles 10..11
#define OFF_XCN2 98304    // tiles 12..19
#define OFF_XCN3 163840   // tiles 20..27
#define OFF_LIN1 229376   // tiles 28..35
#define WT_TOTAL 294912
#define NTILES   36

__host__ __device__ constexpr int tile_off(int t) {
    return t < 2  ? OFF_XIJ1 + t * 8192
         : t < 10 ? OFF_XIJ2 + (t - 2) * 8192
         : t < 12 ? OFF_XCN1 + (t - 10) * 8192
         : t < 20 ? OFF_XCN2 + (t - 12) * 8192
         : t < 28 ? OFF_XCN3 + (t - 20) * 8192
         :          OFF_LIN1 + (t - 28) * 8192;
}

// ---- async global->LDS (LDS dest = wave-uniform base + lane*16B) ----
__device__ __forceinline__ void gll16(const unsigned short* g, unsigned short* l) {
    __builtin_amdgcn_global_load_lds(
        (const __attribute__((address_space(1))) unsigned int*)g,
        (__attribute__((address_space(3))) unsigned int*)l, 16, 0, 0);
}
// 8KB activation tile with 256 threads: 2 gll16/thread
__device__ __forceinline__ void stage_act(const unsigned short* g, unsigned short* l,
                                          int tid, int wv) {
#pragma unroll
    for (int c = 0; c < 2; ++c)
        gll16(g + c * 2048 + tid * 8, l + c * 2048 + wv * 512);
}

// Edge stage (1 edge per wave, latency TLP-hidden at 8192 blocks) + weight-prep piggyback.
// xij/xcn written PRE-SWIZZLED (elem ^= (row&7)<<3) so linear global_load_lds staging
// lands in the swizzled layout the mlp A-fragment ds_reads expect.
__global__ __launch_bounds__(256) void edge_prep_k(const float* __restrict__ x,
                                                   const int* __restrict__ adj,
                                                   const int* __restrict__ tar,
                                                   const float* __restrict__ xij_w1,
                                                   const float* __restrict__ xij_w2,
                                                   const float* __restrict__ xcn_w1,
                                                   const float* __restrict__ xcn_w2,
                                                   const float* __restrict__ xcn_w3,
                                                   const float* __restrict__ lin_w1,
                                                   unsigned short* __restrict__ WT,
                                                   unsigned short* __restrict__ xij_g,
                                                   unsigned short* __restrict__ xcn_g) {
    const int wv   = threadIdx.x >> 6;
    const int lane = threadIdx.x & 63;
    const int e    = blockIdx.x * 4 + wv;      // grid = NEDGES/4 = 8192

    int i = tar[e];
    int j = tar[NEDGES + e];
    int ni = adj[i * DDEG + lane];
    int nj = adj[j * DDEG + lane];
    float xi = x[i * FIN + lane];
    float xj = x[j * FIN + lane];

    bool found = false;
#pragma unroll
    for (int b = 0; b < 64; ++b)
        found |= (ni == (int)__builtin_amdgcn_readlane(nj, b));
    unsigned long long m = __ballot(found);

    float acc = 0.f;
    while (m) {
        int a = __ffsll(m) - 1;
        m &= m - 1;
        int r = (int)__builtin_amdgcn_readlane(ni, a);
        acc += x[r * FIN + lane];
    }
    int sl = lane ^ ((e & 7) << 3);            // pre-swizzle (row&7 == e&7)
    xij_g[(size_t)e * FIN + sl] = f2bf(xi * xj);
    xcn_g[(size_t)e * FIN + sl] = f2bf(acc);

    // ---- weight-prep piggyback: fp32 W[K,256] -> blocked bf16 WT ----
    if (blockIdx.x < WT_TOTAL / 256) {
        int idx = blockIdx.x * 256 + threadIdx.x;
        const float* src;
        int r;
        if (idx < OFF_XIJ2)      { r = idx - OFF_XIJ1; src = xij_w1; }
        else if (idx < OFF_XCN1) { r = idx - OFF_XIJ2; src = xij_w2; }
        else if (idx < OFF_XCN2) { r = idx - OFF_XCN1; src = xcn_w1; }
        else if (idx < OFF_XCN3) { r = idx - OFF_XCN2; src = xcn_w2; }
        else if (idx < OFF_LIN1) { r = idx - OFF_XCN3; src = xcn_w3; }
        else                     { r = idx - OFF_LIN1; src = lin_w1; }
        int kb  = r >> 13;
        int n   = (r & 8191) >> 5;
        int klo = r & 31;
        WT[idx] = f2bf(src[(kb * 32 + klo) * HID + n]);
    }
}

// BARRIER-FREE k-loop phase, B in a 6-slot REGISTER rotation bq[t%6][4].
// Tile t's 4 coalesced 1KB loads were issued at the END of step t-6 (~5 steps of
// slack ~650cy, covering L2 latency under full concurrency; compiler-counted vmcnt
// waits at first use). Per step:
//   ds_read a[4] (shared As, read-only) ; 16 MFMA on bq[t%6] ; then issue loads for
//   tile t+6 into bq[(t+6)%6] — same slot as just-consumed t, so the WAR on those
//   registers pins the issue AFTER the MFMAs. No LDS writes, no barriers.
// acc[4][4]: wave covers all 64 rows x its 64-col group.
template <int T0, int NT, int LDA>
__device__ __forceinline__ void run_phase(const unsigned short* As,
                                          const unsigned short* __restrict__ WT,
                                          int boff, int lr, int lg,
                                          bf16x8 (&bq)[6][4], f32x4 acc[4][4]) {
#pragma unroll
    for (int m = 0; m < 4; ++m)
#pragma unroll
        for (int n = 0; n < 4; ++n) acc[m][n] = (f32x4){0.f, 0.f, 0.f, 0.f};
    const int sw = (lr & 7) << 3;
#pragma unroll
    for (int s = 0; s < NT; ++s) {
        const int t = T0 + s;
        bf16x8 a[4];
#pragma unroll
        for (int m = 0; m < 4; ++m)
            a[m] = *reinterpret_cast<const bf16x8*>(
                &As[(m * 16 + lr) * LDA + ((s * 32 + 8 * lg) ^ sw)]);
        __builtin_amdgcn_s_setprio(1);
#pragma unroll
        for (int m = 0; m < 4; ++m)
#pragma unroll
            for (int n = 0; n < 4; ++n)
                acc[m][n] = __builtin_amdgcn_mfma_f32_16x16x32_bf16(a[m], bq[t % 6][n], acc[m][n], 0, 0, 0);
        __builtin_amdgcn_s_setprio(0);
        if (t + 6 < NTILES) {
#pragma unroll
            for (int n = 0; n < 4; ++n)
                bq[(t + 6) % 6][n] = *reinterpret_cast<const bf16x8*>(
                    &WT[tile_off(t + 6) + boff + n * 512]);
        }
    }
}

__device__ __forceinline__ void fence_barrier() {
    asm volatile("s_waitcnt lgkmcnt(0)" ::: "memory");   // own ds ops drained
    __builtin_amdgcn_s_barrier();                        // global loads stay in flight
}

// MLP over 64-edge tiles; 4 waves (256 thr); grid 512 = exactly 2 independent
// blocks/CU (separate barrier domains). Wave wv: all 64 rows, cols wv*64..+64
// (m4n4). D-frag lane l: row = m*16 + 4*(l>>4) + i, col = col0 + n*16 + (l&15).
// LDS 48 KB (8 sXij + 8 sXcn + 32 sH). __launch_bounds__(256,2): 2 blocks/CU ->
// 8 waves/CU -> 2 waves/EU -> arch-VGPR cap 256 (acc 64 + bq 96 fit, no spill).
// h_ij round-trips through hij_g (same block -> same XCD L2).
__global__ __launch_bounds__(256, 2) void mlp_k(const unsigned short* __restrict__ xij_g,
                                                const unsigned short* __restrict__ xcn_g,
                                                const unsigned short* __restrict__ WT,
                                                unsigned* __restrict__ hij_g,
                                                const float* __restrict__ xij_b1,
                                                const float* __restrict__ xij_b2,
                                                const float* __restrict__ xcn_b1,
                                                const float* __restrict__ xcn_b2,
                                                const float* __restrict__ xcn_b3,
                                                const float* __restrict__ lin_b1,
                                                const float* __restrict__ lin_w2,
                                                const float* __restrict__ lin_b2,
                                                const float* __restrict__ beta,
                                                float* __restrict__ out) {
    __shared__ unsigned short sXij[64 * 64];   // 8 KB, pre-swizzled (aliased as sRed later)
    __shared__ unsigned short sXcn[64 * 64];   // 8 KB, pre-swizzled
    __shared__ unsigned short sH[64 * 256];    // 32 KB activation (in-place reuse)

    const int tid  = threadIdx.x;
    const int wv   = tid >> 6;
    const int lane = tid & 63;
    const int lr   = lane & 15;
    const int lg   = lane >> 4;
    const int col0 = wv * 64;
    const int row0 = blockIdx.x * 64;
    const int boff = (col0 + lr) * 32 + 8 * lg;   // wave's B-slice offset within a tile

    // prologue: stage sXij (2 gll16) + sXcn (2 gll16), then preload B tiles 0..5
    // into the register rotation (24 loads). vmcnt(24) completes the 4 gll16s (FIFO).
    stage_act(xij_g + (size_t)row0 * FIN, sXij, tid, wv);
    stage_act(xcn_g + (size_t)row0 * FIN, sXcn, tid, wv);
    bf16x8 bq[6][4];
#pragma unroll
    for (int t = 0; t < 6; ++t)
#pragma unroll
        for (int n = 0; n < 4; ++n)
            bq[t][n] = *reinterpret_cast<const bf16x8*>(&WT[tile_off(t) + boff + n * 512]);
    const float betaf = beta[0];
    unsigned* hbase = hij_g + (size_t)(blockIdx.x * 4 + wv) * 2048 + lane * 2;
    asm volatile("s_waitcnt vmcnt(24)" ::: "memory");
    __builtin_amdgcn_s_barrier();

    f32x4 acc[4][4];
    float bl[4];

    // ---- P1 (t=0,1): h1 = relu(xij @ xij_w1 + b1) -> sH ----
    run_phase<0, 2, 64>(sXij, WT, boff, lr, lg, bq, acc);
#pragma unroll
    for (int n = 0; n < 4; ++n) bl[n] = xij_b1[col0 + n * 16 + lr];
#pragma unroll
    for (int m = 0; m < 4; ++m)
#pragma unroll
        for (int n = 0; n < 4; ++n)
#pragma unroll
            for (int i = 0; i < 4; ++i) {
                int row = m * 16 + 4 * lg + i;
                int col = col0 + n * 16 + lr;
                sH[row * HID + (col ^ ((row & 7) << 3))] = f2bf(fmaxf(acc[m][n][i] + bl[n], 0.f));
            }
    fence_barrier();   // B1: sH(h1) visible to all waves

    // ---- P2 (t=2..9): h_ij = h1 @ xij_w2 + b2 -> hij_g (L2-resident round-trip) ----
    run_phase<2, 8, 256>(sH, WT, boff, lr, lg, bq, acc);
#pragma unroll
    for (int n = 0; n < 4; ++n) bl[n] = xij_b2[col0 + n * 16 + lr];
#pragma unroll
    for (int m = 0; m < 4; ++m)
#pragma unroll
        for (int n = 0; n < 4; ++n) {
            uint2 v;
            v.x = ((unsigned)f2bf(acc[m][n][1] + bl[n]) << 16) | f2bf(acc[m][n][0] + bl[n]);
            v.y = ((unsigned)f2bf(acc[m][n][3] + bl[n]) << 16) | f2bf(acc[m][n][2] + bl[n]);
            *reinterpret_cast<uint2*>(hbase + (m * 4 + n) * 128) = v;
        }
    fence_barrier();   // B2: all waves' sH(h1) reads done; P3 epi may overwrite sH

    // ---- P3 (t=10,11): t1 = relu(xcn @ xcn_w1 + b1) -> sH ----
    run_phase<10, 2, 64>(sXcn, WT, boff, lr, lg, bq, acc);
#pragma unroll
    for (int n = 0; n < 4; ++n) bl[n] = xcn_b1[col0 + n * 16 + lr];
#pragma unroll
    for (int m = 0; m < 4; ++m)
#pragma unroll
        for (int n = 0; n < 4; ++n)
#pragma unroll
            for (int i = 0; i < 4; ++i) {
                int row = m * 16 + 4 * lg + i;
                int col = col0 + n * 16 + lr;
                sH[row * HID + (col ^ ((row & 7) << 3))] = f2bf(fmaxf(acc[m][n][i] + bl[n], 0.f));
            }
    fence_barrier();   // B3: sH(t1) visible

    // ---- P4 (t=12..19): t2 = relu(t1 @ xcn_w2 + b2) -> sH IN PLACE ----
    run_phase<12, 8, 256>(sH, WT, boff, lr, lg, bq, acc);
    fence_barrier();   // B4: all waves' t1 reads done before overwrite
#pragma unroll
    for (int n = 0; n < 4; ++n) bl[n] = xcn_b2[col0 + n * 16 + lr];
#pragma unroll
    for (int m = 0; m < 4; ++m)
#pragma unroll
        for (int n = 0; n < 4; ++n)
#pragma unroll
            for (int i = 0; i < 4; ++i) {
                int row = m * 16 + 4 * lg + i;
                int col = col0 + n * 16 + lr;
                sH[row * HID + (col ^ ((row & 7) << 3))] = f2bf(fmaxf(acc[m][n][i] + bl[n], 0.f));
            }
    fence_barrier();   // B5: sH(t2) visible

    // ---- P5 (t=20..27): u = (t2 @ xcn_w3 + b3) * beta + h_ij -> sH IN PLACE ----
    run_phase<20, 8, 256>(sH, WT, boff, lr, lg, bq, acc);
    fence_barrier();   // B6: all waves' t2 reads done
#pragma unroll
    for (int n = 0; n < 4; ++n) bl[n] = xcn_b3[col0 + n * 16 + lr];
#pragma unroll
    for (int m = 0; m < 4; ++m)
#pragma unroll
        for (int n = 0; n < 4; ++n) {
            uint2 v = *reinterpret_cast<const uint2*>(hbase + (m * 4 + n) * 128);
            float h0 = b2f((unsigned short)(v.x & 0xFFFF));
            float h1 = b2f((unsigned short)(v.x >> 16));
            float h2 = b2f((unsigned short)(v.y & 0xFFFF));
            float h3 = b2f((unsigned short)(v.y >> 16));
            float v0 = (acc[m][n][0] + bl[n]) * betaf + h0;
            float v1 = (acc[m][n][1] + bl[n]) * betaf + h1;
            float v2 = (acc[m][n][2] + bl[n]) * betaf + h2;
            float v3 = (acc[m][n][3] + bl[n]) * betaf + h3;
            int rb = m * 16 + 4 * lg;
            int col = col0 + n * 16 + lr;
            sH[(rb + 0) * HID + (col ^ (((rb + 0) & 7) << 3))] = f2bf(v0);
            sH[(rb + 1) * HID + (col ^ (((rb + 1) & 7) << 3))] = f2bf(v1);
            sH[(rb + 2) * HID + (col ^ (((rb + 2) & 7) << 3))] = f2bf(v2);
            sH[(rb + 3) * HID + (col ^ (((rb + 3) & 7) << 3))] = f2bf(v3);
        }
    fence_barrier();   // B7: sH(u) visible

    // ---- P6 (t=28..35): out = relu(u @ lin_w1 + lb1) . lin_w2 + lb2 ----
    run_phase<28, 8, 256>(sH, WT, boff, lr, lg, bq, acc);
#pragma unroll
    for (int n = 0; n < 4; ++n) bl[n] = lin_b1[col0 + n * 16 + lr];
    float w2l[4];
#pragma unroll
    for (int n = 0; n < 4; ++n) w2l[n] = lin_w2[col0 + n * 16 + lr];
    float* sRed = (float*)sXij;   // sXij dead since P1; 4 col-groups x 64 rows f32 (1 KB)
#pragma unroll
    for (int m = 0; m < 4; ++m) {
        float p[4] = {0.f, 0.f, 0.f, 0.f};
#pragma unroll
        for (int n = 0; n < 4; ++n)
#pragma unroll
            for (int i = 0; i < 4; ++i)
                p[i] += fmaxf(acc[m][n][i] + bl[n], 0.f) * w2l[n];
#pragma unroll
        for (int i = 0; i < 4; ++i) {
            float s = p[i];
            s += __shfl_xor(s, 1);
            s += __shfl_xor(s, 2);
            s += __shfl_xor(s, 4);
            s += __shfl_xor(s, 8);
            if (lr == 0) sRed[wv * 64 + m * 16 + 4 * lg + i] = s;
        }
    }
    __syncthreads();
    if (tid < 64)
        out[row0 + tid] = sRed[tid] + sRed[64 + tid] + sRed[128 + tid] + sRed[192 + tid] + lin_b2[0];
}

extern "C" void kernel_launch(void* const* d_in, const int* in_sizes, int n_in,
                              void* d_out, int out_size, void* d_ws, size_t ws_size,
                              hipStream_t stream) {
    const float* x      = (const float*)d_in[0];
    const int*   adj    = (const int*)d_in[1];
    const int*   tar    = (const int*)d_in[2];
    const float* beta   = (const float*)d_in[3];
    const float* xcn_w1 = (const float*)d_in[4];
    const float* xcn_b1 = (const float*)d_in[5];
    const float* xcn_w2 = (const float*)d_in[6];
    const float* xcn_b2 = (const float*)d_in[7];
    const float* xcn_w3 = (const float*)d_in[8];
    const float* xcn_b3 = (const float*)d_in[9];
    const float* xij_w1 = (const float*)d_in[10];
    const float* xij_b1 = (const float*)d_in[11];
    const float* xij_w2 = (const float*)d_in[12];
    const float* xij_b2 = (const float*)d_in[13];
    const float* lin_w1 = (const float*)d_in[14];
    const float* lin_b1 = (const float*)d_in[15];
    const float* lin_w2 = (const float*)d_in[16];
    const float* lin_b2 = (const float*)d_in[17];

    unsigned short* WT    = (unsigned short*)d_ws;                     // 576 KiB
    unsigned short* xij_g = (unsigned short*)((char*)d_ws + 589824);   // 4 MiB
    unsigned short* xcn_g = (unsigned short*)((char*)d_ws + 4784128);  // 4 MiB
    unsigned*       hij_g = (unsigned*)((char*)d_ws + 8978432);        // 16 MiB

    edge_prep_k<<<NEDGES / 4, 256, 0, stream>>>(x, adj, tar,
                                                xij_w1, xij_w2, xcn_w1, xcn_w2, xcn_w3, lin_w1,
                                                WT, xij_g, xcn_g);
    mlp_k<<<NEDGES / 64, 256, 0, stream>>>(xij_g, xcn_g, WT, hij_g,
                                           xij_b1, xij_b2, xcn_b1, xcn_b2, xcn_b3,
                                           lin_b1, lin_w2, lin_b2, beta, (float*)d_out);
}

// Round 20
// 59.991 us; speedup vs baseline: 1.2319x; 1.1621x over previous
//
#include <hip/hip_runtime.h>

// Problem constants (from reference)
#define NNODES 10000
#define DDEG   64
#define NEDGES 32768
#define FIN    64
#define HID    256

typedef __attribute__((ext_vector_type(8))) __bf16 bf16x8;
typedef __attribute__((ext_vector_type(4))) float  f32x4;

__device__ __forceinline__ unsigned short f2bf(float f) {
    unsigned x = __float_as_uint(f);
    return (unsigned short)((x + 0x7FFFu + ((x >> 16) & 1u)) >> 16);  // RNE
}
__device__ __forceinline__ float b2f(unsigned short u) {
    return __uint_as_float(((unsigned)u) << 16);
}

// Blocked transposed-weight layout (bf16): WT[k>>5][n][k&31], tile = 8192 elems (16KB).
#define OFF_XIJ1 0        // K=64  : tiles 0..1
#define OFF_XIJ2 16384    // K=256 : tiles 2..9
#define OFF_XCN1 81920    // tiles 10..11
#define OFF_XCN2 98304    // tiles 12..19
#define OFF_XCN3 163840   // tiles 20..27
#define OFF_LIN1 229376   // tiles 28..35
#define WT_TOTAL 294912
#define NTILES   36

__host__ __device__ constexpr int tile_off(int t) {
    return t < 2  ? OFF_XIJ1 + t * 8192
         : t < 10 ? OFF_XIJ2 + (t - 2) * 8192
         : t < 12 ? OFF_XCN1 + (t - 10) * 8192
         : t < 20 ? OFF_XCN2 + (t - 12) * 8192
         : t < 28 ? OFF_XCN3 + (t - 20) * 8192
         :          OFF_LIN1 + (t - 28) * 8192;
}

// ---- async global->LDS (LDS dest = wave-uniform base + lane*16B) ----
__device__ __forceinline__ void gll16(const unsigned short* g, unsigned short* l) {
    __builtin_amdgcn_global_load_lds(
        (const __attribute__((address_space(1))) unsigned int*)g,
        (__attribute__((address_space(3))) unsigned int*)l, 16, 0, 0);
}
// 16KB tile with 512 threads: 2 gll16/thread (vmcnt +2/wave)
__device__ __forceinline__ void stage16(const unsigned short* g, unsigned short* l,
                                        int tid, int wv) {
#pragma unroll
    for (int c = 0; c < 2; ++c)
        gll16(g + c * 4096 + tid * 8, l + c * 4096 + wv * 512);
}

// Edge stage (1 edge per wave, latency TLP-hidden at 8192 blocks) + weight-prep piggyback.
// xij/xcn written PRE-SWIZZLED (elem ^= (row&7)<<3) so linear global_load_lds staging
// lands in the swizzled layout the mlp A-fragment ds_reads expect.
__global__ __launch_bounds__(256) void edge_prep_k(const float* __restrict__ x,
                                                   const int* __restrict__ adj,
                                                   const int* __restrict__ tar,
                                                   const float* __restrict__ xij_w1,
                                                   const float* __restrict__ xij_w2,
                                                   const float* __restrict__ xcn_w1,
                                                   const float* __restrict__ xcn_w2,
                                                   const float* __restrict__ xcn_w3,
                                                   const float* __restrict__ lin_w1,
                                                   unsigned short* __restrict__ WT,
                                                   unsigned short* __restrict__ xij_g,
                                                   unsigned short* __restrict__ xcn_g) {
    const int wv   = threadIdx.x >> 6;
    const int lane = threadIdx.x & 63;
    const int e    = blockIdx.x * 4 + wv;      // grid = NEDGES/4 = 8192

    int i = tar[e];
    int j = tar[NEDGES + e];
    int ni = adj[i * DDEG + lane];
    int nj = adj[j * DDEG + lane];
    float xi = x[i * FIN + lane];
    float xj = x[j * FIN + lane];

    bool found = false;
#pragma unroll
    for (int b = 0; b < 64; ++b)
        found |= (ni == (int)__builtin_amdgcn_readlane(nj, b));
    unsigned long long m = __ballot(found);

    float acc = 0.f;
    while (m) {
        int a = __ffsll(m) - 1;
        m &= m - 1;
        int r = (int)__builtin_amdgcn_readlane(ni, a);
        acc += x[r * FIN + lane];
    }
    int sl = lane ^ ((e & 7) << 3);            // pre-swizzle (row&7 == e&7)
    xij_g[(size_t)e * FIN + sl] = f2bf(xi * xj);
    xcn_g[(size_t)e * FIN + sl] = f2bf(acc);

    // ---- weight-prep piggyback: fp32 W[K,256] -> blocked bf16 WT ----
    if (blockIdx.x < WT_TOTAL / 256) {
        int idx = blockIdx.x * 256 + threadIdx.x;
        const float* src;
        int r;
        if (idx < OFF_XIJ2)      { r = idx - OFF_XIJ1; src = xij_w1; }
        else if (idx < OFF_XCN1) { r = idx - OFF_XIJ2; src = xij_w2; }
        else if (idx < OFF_XCN2) { r = idx - OFF_XCN1; src = xcn_w1; }
        else if (idx < OFF_XCN3) { r = idx - OFF_XCN2; src = xcn_w2; }
        else if (idx < OFF_LIN1) { r = idx - OFF_XCN3; src = xcn_w3; }
        else                     { r = idx - OFF_LIN1; src = lin_w1; }
        int kb  = r >> 13;
        int n   = (r & 8191) >> 5;
        int klo = r & 31;
        WT[idx] = f2bf(src[(kb * 32 + klo) * HID + n]);
    }
}

// One phase of the continuous 36-tile stream. 4-slot LDS ring, 3-step staging slack
// (tile t staged at step t-3, waited at step t). Per step t:
//   s_waitcnt vmcnt(4) lgkmcnt(0)  // tile t landed (t+1,t+2 outstanding); own prior
//                                  // ds ops drained before barrier (WAR + visibility)
//   s_barrier                      // all waves synced; slot (t+3)&3 = (t-1)&3 whose
//                                  // readers ran at step t-1 and drained above
//   stage tile t+3 into slot (t+3)&3   [+ optional sX restage at P2 entry]
//   ds_read B(4)+A(4); 16 MFMA (setprio)
// acc[4][4]: wave tile rows r0..r0+64, cols col0..col0+64.
template <int T0, int NT, int LDA, bool RESTAGE>
__device__ __forceinline__ void run_phase(const unsigned short* As,
                                          unsigned short* ring,
                                          const unsigned short* __restrict__ WT,
                                          const unsigned short* __restrict__ restage_src,
                                          unsigned short* sX,
                                          int lr, int lg, int col0, int r0,
                                          int tid, int wv, f32x4 acc[4][4]) {
#pragma unroll
    for (int m = 0; m < 4; ++m)
#pragma unroll
        for (int n = 0; n < 4; ++n) acc[m][n] = (f32x4){0.f, 0.f, 0.f, 0.f};
    const int sw = (lr & 7) << 3;
#pragma unroll
    for (int s = 0; s < NT; ++s) {
        const int t = T0 + s;
        if (t <= NTILES - 3)
            asm volatile("s_waitcnt vmcnt(4) lgkmcnt(0)" ::: "memory");
        else if (t == NTILES - 2)
            asm volatile("s_waitcnt vmcnt(2) lgkmcnt(0)" ::: "memory");
        else
            asm volatile("s_waitcnt vmcnt(0) lgkmcnt(0)" ::: "memory");
        __builtin_amdgcn_s_barrier();
        if (t + 3 < NTILES)
            stage16(WT + tile_off(t + 3), ring + ((t + 3) & 3) * 8192, tid, wv);
        if (RESTAGE && s == 0)
            stage16(restage_src, sX, tid, wv);   // sX readers fenced by this barrier
        const unsigned short* cur = ring + (t & 3) * 8192;
        bf16x8 a[4], b[4];
#pragma unroll
        for (int n = 0; n < 4; ++n)
            b[n] = *reinterpret_cast<const bf16x8*>(&cur[(col0 + n * 16 + lr) * 32 + 8 * lg]);
#pragma unroll
        for (int m = 0; m < 4; ++m)
            a[m] = *reinterpret_cast<const bf16x8*>(
                &As[(r0 + m * 16 + lr) * LDA + ((s * 32 + 8 * lg) ^ sw)]);
        __builtin_amdgcn_s_setprio(1);
#pragma unroll
        for (int m = 0; m < 4; ++m)
#pragma unroll
            for (int n = 0; n < 4; ++n)
                acc[m][n] = __builtin_amdgcn_mfma_f32_16x16x32_bf16(a[m], b[n], acc[m][n], 0, 0, 0);
        __builtin_amdgcn_s_setprio(0);
    }
}

__device__ __forceinline__ void fence_barrier() {
    asm volatile("s_waitcnt lgkmcnt(0)" ::: "memory");   // own ds ops drained
    __builtin_amdgcn_s_barrier();                        // staged loads stay in flight
}

// MLP over 128-edge tiles; 8 waves (512 thr); grid 256 = 1 block/CU, ONE pass.
// Wave wv: rows r0=(wv>>2)*64..+64, cols col0=(wv&3)*64..+64 (m4n4 fragments).
// D-frag lane l: row = r0 + m*16 + 4*(l>>4) + i, col = col0 + n*16 + (l&15).
// LDS 144 KB (16 sX + 64 sH + 64 ring). Unified reg demand ~125 <= 128 cap at
// (512,1) (r12/r19 evidence: VGPR_Count is the unified budget; hij must go via L2).
// B L2-traffic and tile-steps/CU both HALVED vs 64-edge tiling.
__global__ __launch_bounds__(512, 1) void mlp_k(const unsigned short* __restrict__ xij_g,
                                                const unsigned short* __restrict__ xcn_g,
                                                const unsigned short* __restrict__ WT,
                                                unsigned* __restrict__ hij_g,
                                                const float* __restrict__ xij_b1,
                                                const float* __restrict__ xij_b2,
                                                const float* __restrict__ xcn_b1,
                                                const float* __restrict__ xcn_b2,
                                                const float* __restrict__ xcn_b3,
                                                const float* __restrict__ lin_b1,
                                                const float* __restrict__ lin_w2,
                                                const float* __restrict__ lin_b2,
                                                const float* __restrict__ beta,
                                                float* __restrict__ out) {
    __shared__ unsigned short sX[128 * 64];    // 16 KB: xij (P1), xcn (P3); sRed later
    __shared__ unsigned short sH[128 * 256];   // 64 KB activation (in-place reuse)
    __shared__ unsigned short sB[4 * 8192];    // 64 KB: 4-slot weight ring

    const int tid  = threadIdx.x;
    const int wv   = tid >> 6;
    const int lane = tid & 63;
    const int lr   = lane & 15;
    const int lg   = lane >> 4;
    const int r0   = (wv >> 2) * 64;
    const int col0 = (wv & 3) * 64;
    const int row0 = blockIdx.x * 128;

    // prologue: sX<-xij (2) + tiles 0,1,2 (6) = 8 outstanding/wave.
    // Step t=0's vmcnt(4) completes sX+tile0 (FIFO); tiles 1,2 stay in flight.
    stage16(xij_g + (size_t)row0 * FIN, sX, tid, wv);
    stage16(WT + tile_off(0), sB, tid, wv);
    stage16(WT + tile_off(1), sB + 8192, tid, wv);
    stage16(WT + tile_off(2), sB + 16384, tid, wv);
    const float betaf = beta[0];
    unsigned* hbase = hij_g + (size_t)(blockIdx.x * 8 + wv) * 2048 + lane * 2;

    f32x4 acc[4][4];
    float bl[4];

    // ---- P1 (t=0,1): h1 = relu(xij @ xij_w1 + b1) -> sH ----
    run_phase<0, 2, 64, false>(sX, sB, WT, nullptr, nullptr, lr, lg, col0, r0, tid, wv, acc);
#pragma unroll
    for (int n = 0; n < 4; ++n) bl[n] = xij_b1[col0 + n * 16 + lr];
#pragma unroll
    for (int m = 0; m < 4; ++m)
#pragma unroll
        for (int n = 0; n < 4; ++n)
#pragma unroll
            for (int i = 0; i < 4; ++i) {
                int row = r0 + m * 16 + 4 * lg + i;
                int col = col0 + n * 16 + lr;
                sH[row * HID + (col ^ ((row & 7) << 3))] = f2bf(fmaxf(acc[m][n][i] + bl[n], 0.f));
            }
    // sH writes drained+fenced by P2 step0's lgkm0+barrier before any wave reads sH

    // ---- P2 (t=2..9): h_ij = h1 @ xij_w2 + b2 -> hij_g (same-XCD L2 round-trip);
    //      restages sX <- xcn at step0 (xij readers fenced behind that barrier) ----
    run_phase<2, 8, 256, true>(sH, sB, WT, xcn_g + (size_t)row0 * FIN, sX,
                               lr, lg, col0, r0, tid, wv, acc);
#pragma unroll
    for (int n = 0; n < 4; ++n) bl[n] = xij_b2[col0 + n * 16 + lr];
#pragma unroll
    for (int m = 0; m < 4; ++m)
#pragma unroll
        for (int n = 0; n < 4; ++n) {
            uint2 v;
            v.x = ((unsigned)f2bf(acc[m][n][1] + bl[n]) << 16) | f2bf(acc[m][n][0] + bl[n]);
            v.y = ((unsigned)f2bf(acc[m][n][3] + bl[n]) << 16) | f2bf(acc[m][n][2] + bl[n]);
            *reinterpret_cast<uint2*>(hbase + (m * 4 + n) * 128) = v;
        }

    // ---- P3 (t=10,11): t1 = relu(xcn @ xcn_w1 + b1) -> sH (P2's sH reads fenced by
    //      P3 step0's lgkm0+barrier before these epilogue writes land) ----
    run_phase<10, 2, 64, false>(sX, sB, WT, nullptr, nullptr, lr, lg, col0, r0, tid, wv, acc);
#pragma unroll
    for (int n = 0; n < 4; ++n) bl[n] = xcn_b1[col0 + n * 16 + lr];
#pragma unroll
    for (int m = 0; m < 4; ++m)
#pragma unroll
        for (int n = 0; n < 4; ++n)
#pragma unroll
            for (int i = 0; i < 4; ++i) {
                int row = r0 + m * 16 + 4 * lg + i;
                int col = col0 + n * 16 + lr;
                sH[row * HID + (col ^ ((row & 7) << 3))] = f2bf(fmaxf(acc[m][n][i] + bl[n], 0.f));
            }

    // ---- P4 (t=12..19): t2 = relu(t1 @ xcn_w2 + b2) -> sH IN PLACE ----
    run_phase<12, 8, 256, false>(sH, sB, WT, nullptr, nullptr, lr, lg, col0, r0, tid, wv, acc);
    fence_barrier();   // all waves' t1 reads done before overwrite
#pragma unroll
    for (int n = 0; n < 4; ++n) bl[n] = xcn_b2[col0 + n * 16 + lr];
#pragma unroll
    for (int m = 0; m < 4; ++m)
#pragma unroll
        for (int n = 0; n < 4; ++n)
#pragma unroll
            for (int i = 0; i < 4; ++i) {
                int row = r0 + m * 16 + 4 * lg + i;
                int col = col0 + n * 16 + lr;
                sH[row * HID + (col ^ ((row & 7) << 3))] = f2bf(fmaxf(acc[m][n][i] + bl[n], 0.f));
            }

    // ---- P5 (t=20..27): u = (t2 @ xcn_w3 + b3) * beta + h_ij -> sH IN PLACE ----
    run_phase<20, 8, 256, false>(sH, sB, WT, nullptr, nullptr, lr, lg, col0, r0, tid, wv, acc);
    fence_barrier();   // all waves' t2 reads done
#pragma unroll
    for (int n = 0; n < 4; ++n) bl[n] = xcn_b3[col0 + n * 16 + lr];
#pragma unroll
    for (int m = 0; m < 4; ++m)
#pragma unroll
        for (int n = 0; n < 4; ++n) {
            uint2 v = *reinterpret_cast<const uint2*>(hbase + (m * 4 + n) * 128);
            float h0 = b2f((unsigned short)(v.x & 0xFFFF));
            float h1 = b2f((unsigned short)(v.x >> 16));
            float h2 = b2f((unsigned short)(v.y & 0xFFFF));
            float h3 = b2f((unsigned short)(v.y >> 16));
            float v0 = (acc[m][n][0] + bl[n]) * betaf + h0;
            float v1 = (acc[m][n][1] + bl[n]) * betaf + h1;
            float v2 = (acc[m][n][2] + bl[n]) * betaf + h2;
            float v3 = (acc[m][n][3] + bl[n]) * betaf + h3;
            int rb = r0 + m * 16 + 4 * lg;
            int col = col0 + n * 16 + lr;
            sH[(rb + 0) * HID + (col ^ (((rb + 0) & 7) << 3))] = f2bf(v0);
            sH[(rb + 1) * HID + (col ^ (((rb + 1) & 7) << 3))] = f2bf(v1);
            sH[(rb + 2) * HID + (col ^ (((rb + 2) & 7) << 3))] = f2bf(v2);
            sH[(rb + 3) * HID + (col ^ (((rb + 3) & 7) << 3))] = f2bf(v3);
        }
    fence_barrier();   // sH(u) visible before P6 reads

    // ---- P6 (t=28..35): out = relu(u @ lin_w1 + lb1) . lin_w2 + lb2 ----
    run_phase<28, 8, 256, false>(sH, sB, WT, nullptr, nullptr, lr, lg, col0, r0, tid, wv, acc);
#pragma unroll
    for (int n = 0; n < 4; ++n) bl[n] = lin_b1[col0 + n * 16 + lr];
    float w2l[4];
#pragma unroll
    for (int n = 0; n < 4; ++n) w2l[n] = lin_w2[col0 + n * 16 + lr];
    float* sRed = (float*)sX;   // sX dead since P3; 4 col-groups x 128 rows f32 (2 KB)
#pragma unroll
    for (int m = 0; m < 4; ++m) {
        float p[4] = {0.f, 0.f, 0.f, 0.f};
#pragma unroll
        for (int n = 0; n < 4; ++n)
#pragma unroll
            for (int i = 0; i < 4; ++i)
                p[i] += fmaxf(acc[m][n][i] + bl[n], 0.f) * w2l[n];
#pragma unroll
        for (int i = 0; i < 4; ++i) {
            float s = p[i];
            s += __shfl_xor(s, 1);
            s += __shfl_xor(s, 2);
            s += __shfl_xor(s, 4);
            s += __shfl_xor(s, 8);
            if (lr == 0) sRed[(wv & 3) * 128 + r0 + m * 16 + 4 * lg + i] = s;
        }
    }
    __syncthreads();   // stream fully drained (t=35 waited vmcnt(0))
    if (tid < 128)
        out[row0 + tid] = sRed[tid] + sRed[128 + tid] + sRed[256 + tid] + sRed[384 + tid] + lin_b2[0];
}

extern "C" void kernel_launch(void* const* d_in, const int* in_sizes, int n_in,
                              void* d_out, int out_size, void* d_ws, size_t ws_size,
                              hipStream_t stream) {
    const float* x      = (const float*)d_in[0];
    const int*   adj    = (const int*)d_in[1];
    const int*   tar    = (const int*)d_in[2];
    const float* beta   = (const float*)d_in[3];
    const float* xcn_w1 = (const float*)d_in[4];
    const float* xcn_b1 = (const float*)d_in[5];
    const float* xcn_w2 = (const float*)d_in[6];
    const float* xcn_b2 = (const float*)d_in[7];
    const float* xcn_w3 = (const float*)d_in[8];
    const float* xcn_b3 = (const float*)d_in[9];
    const float* xij_w1 = (const float*)d_in[10];
    const float* xij_b1 = (const float*)d_in[11];
    const float* xij_w2 = (const float*)d_in[12];
    const float* xij_b2 = (const float*)d_in[13];
    const float* lin_w1 = (const float*)d_in[14];
    const float* lin_b1 = (const float*)d_in[15];
    const float* lin_w2 = (const float*)d_in[16];
    const float* lin_b2 = (const float*)d_in[17];

    unsigned short* WT    = (unsigned short*)d_ws;                     // 576 KiB
    unsigned short* xij_g = (unsigned short*)((char*)d_ws + 589824);   // 4 MiB
    unsigned short* xcn_g = (unsigned short*)((char*)d_ws + 4784128);  // 4 MiB
    unsigned*       hij_g = (unsigned*)((char*)d_ws + 8978432);        // 16 MiB

    edge_prep_k<<<NEDGES / 4, 256, 0, stream>>>(x, adj, tar,
                                                xij_w1, xij_w2, xcn_w1, xcn_w2, xcn_w3, lin_w1,
                                                WT, xij_g, xcn_g);
    mlp_k<<<NEDGES / 128, 512, 0, stream>>>(xij_g, xcn_g, WT, hij_g,
                                            xij_b1, xij_b2, xcn_b1, xcn_b2, xcn_b3,
                                            lin_b1, lin_w2, lin_b2, beta, (float*)d_out);
}

// Round 21
// 58.316 us; speedup vs baseline: 1.2673x; 1.0287x over previous
//
#include <hip/hip_runtime.h>

// Problem constants (from reference)
#define NNODES 10000
#define DDEG   64
#define NEDGES 32768
#define FIN    64
#define HID    256

typedef __attribute__((ext_vector_type(8))) __bf16 bf16x8;
typedef __attribute__((ext_vector_type(4))) float  f32x4;

__device__ __forceinline__ unsigned short f2bf(float f) {
    unsigned x = __float_as_uint(f);
    return (unsigned short)((x + 0x7FFFu + ((x >> 16) & 1u)) >> 16);  // RNE
}
__device__ __forceinline__ float b2f(unsigned short u) {
    return __uint_as_float(((unsigned)u) << 16);
}

// Blocked transposed-weight layout (bf16): WT[k>>5][n][k&31], tile = 8192 elems (16KB).
// Within a tile, col c's 32-k slice (64B) is contiguous; a wave's 16-col B-load is
// 1KB fully coalesced.
#define OFF_XIJ1 0        // K=64  : tiles 0..1
#define OFF_XIJ2 16384    // K=256 : tiles 2..9
#define OFF_XCN1 81920    // tiles 10..11
#define OFF_XCN2 98304    // tiles 12..19
#define OFF_XCN3 163840   // tiles 20..27
#define OFF_LIN1 229376   // tiles 28..35
#define WT_TOTAL 294912
#define NTILES   36

__host__ __device__ constexpr int tile_off(int t) {
    return t < 2  ? OFF_XIJ1 + t * 8192
         : t < 10 ? OFF_XIJ2 + (t - 2) * 8192
         : t < 12 ? OFF_XCN1 + (t - 10) * 8192
         : t < 20 ? OFF_XCN2 + (t - 12) * 8192
         : t < 28 ? OFF_XCN3 + (t - 20) * 8192
         :          OFF_LIN1 + (t - 28) * 8192;
}

// ---- async global->LDS (LDS dest = wave-uniform base + lane*16B) ----
__device__ __forceinline__ void gll16(const unsigned short* g, unsigned short* l) {
    __builtin_amdgcn_global_load_lds(
        (const __attribute__((address_space(1))) unsigned int*)g,
        (__attribute__((address_space(3))) unsigned int*)l, 16, 0, 0);
}
// 8KB activation tile with 256 threads: 2 gll16/thread
__device__ __forceinline__ void stage_act(const unsigned short* g, unsigned short* l,
                                          int tid, int wv) {
#pragma unroll
    for (int c = 0; c < 2; ++c)
        gll16(g + c * 2048 + tid * 8, l + c * 2048 + wv * 512);
}

// Edge stage (1 edge per wave, latency TLP-hidden at 8192 blocks) + weight-prep piggyback.
// xij/xcn written PRE-SWIZZLED (elem ^= (row&7)<<3) so linear global_load_lds staging
// lands in the swizzled layout the mlp A-fragment ds_reads expect.
__global__ __launch_bounds__(256) void edge_prep_k(const float* __restrict__ x,
                                                   const int* __restrict__ adj,
                                                   const int* __restrict__ tar,
                                                   const float* __restrict__ xij_w1,
                                                   const float* __restrict__ xij_w2,
                                                   const float* __restrict__ xcn_w1,
                                                   const float* __restrict__ xcn_w2,
                                                   const float* __restrict__ xcn_w3,
                                                   const float* __restrict__ lin_w1,
                                                   unsigned short* __restrict__ WT,
                                                   unsigned short* __restrict__ xij_g,
                                                   unsigned short* __restrict__ xcn_g) {
    const int wv   = threadIdx.x >> 6;
    const int lane = threadIdx.x & 63;
    const int e    = blockIdx.x * 4 + wv;      // grid = NEDGES/4 = 8192

    int i = tar[e];
    int j = tar[NEDGES + e];
    int ni = adj[i * DDEG + lane];
    int nj = adj[j * DDEG + lane];
    float xi = x[i * FIN + lane];
    float xj = x[j * FIN + lane];

    bool found = false;
#pragma unroll
    for (int b = 0; b < 64; ++b)
        found |= (ni == (int)__builtin_amdgcn_readlane(nj, b));
    unsigned long long m = __ballot(found);

    float acc = 0.f;
    while (m) {
        int a = __ffsll(m) - 1;
        m &= m - 1;
        int r = (int)__builtin_amdgcn_readlane(ni, a);
        acc += x[r * FIN + lane];
    }
    int sl = lane ^ ((e & 7) << 3);            // pre-swizzle (row&7 == e&7)
    xij_g[(size_t)e * FIN + sl] = f2bf(xi * xj);
    xcn_g[(size_t)e * FIN + sl] = f2bf(acc);

    // ---- weight-prep piggyback: fp32 W[K,256] -> blocked bf16 WT ----
    if (blockIdx.x < WT_TOTAL / 256) {
        int idx = blockIdx.x * 256 + threadIdx.x;
        const float* src;
        int r;
        if (idx < OFF_XIJ2)      { r = idx - OFF_XIJ1; src = xij_w1; }
        else if (idx < OFF_XCN1) { r = idx - OFF_XIJ2; src = xij_w2; }
        else if (idx < OFF_XCN2) { r = idx - OFF_XCN1; src = xcn_w1; }
        else if (idx < OFF_XCN3) { r = idx - OFF_XCN2; src = xcn_w2; }
        else if (idx < OFF_LIN1) { r = idx - OFF_XCN3; src = xcn_w3; }
        else                     { r = idx - OFF_LIN1; src = lin_w1; }
        int kb  = r >> 13;
        int n   = (r & 8191) >> 5;
        int klo = r & 31;
        WT[idx] = f2bf(src[(kb * 32 + klo) * HID + n]);
    }
}

// BARRIER-FREE k-loop phase, B in a 4-slot REGISTER rotation bq[t&3][4].
// Tile t's 4 coalesced 1KB loads were issued at the END of step t-4 (~3 steps of
// slack, compiler-counted vmcnt waits at first use). Per step:
//   ds_read a[4] (shared As, read-only) ; 16 MFMA on bq[t&3] ; then issue loads for
//   tile t+4 into bq[(t+4)&3] — same slot as just-consumed t, so the WAR on those
//   registers pins the issue AFTER the MFMAs. No LDS writes, no barriers.
// acc[4][4]: wave covers all 64 rows x its 64-col group.
template <int T0, int NT, int LDA>
__device__ __forceinline__ void run_phase(const unsigned short* As,
                                          const unsigned short* __restrict__ WT,
                                          int boff, int lr, int lg,
                                          bf16x8 (&bq)[4][4], f32x4 acc[4][4]) {
#pragma unroll
    for (int m = 0; m < 4; ++m)
#pragma unroll
        for (int n = 0; n < 4; ++n) acc[m][n] = (f32x4){0.f, 0.f, 0.f, 0.f};
    const int sw = (lr & 7) << 3;
#pragma unroll
    for (int s = 0; s < NT; ++s) {
        const int t = T0 + s;
        bf16x8 a[4];
#pragma unroll
        for (int m = 0; m < 4; ++m)
            a[m] = *reinterpret_cast<const bf16x8*>(
                &As[(m * 16 + lr) * LDA + ((s * 32 + 8 * lg) ^ sw)]);
        __builtin_amdgcn_s_setprio(1);
#pragma unroll
        for (int m = 0; m < 4; ++m)
#pragma unroll
            for (int n = 0; n < 4; ++n)
                acc[m][n] = __builtin_amdgcn_mfma_f32_16x16x32_bf16(a[m], bq[t & 3][n], acc[m][n], 0, 0, 0);
        __builtin_amdgcn_s_setprio(0);
        if (t + 4 < NTILES) {
#pragma unroll
            for (int n = 0; n < 4; ++n)
                bq[(t + 4) & 3][n] = *reinterpret_cast<const bf16x8*>(
                    &WT[tile_off(t + 4) + boff + n * 512]);
        }
    }
}

__device__ __forceinline__ void fence_barrier() {
    asm volatile("s_waitcnt lgkmcnt(0)" ::: "memory");   // own ds ops drained
    __builtin_amdgcn_s_barrier();                        // global loads stay in flight
}

// MLP over 64-edge tiles; 4 waves (256 thr); grid 512 = exactly 2 independent
// blocks/CU (separate barrier domains). Wave wv: all 64 rows, cols wv*64..+64
// (m4n4). D-frag lane l: row = m*16 + 4*(l>>4) + i, col = col0 + n*16 + (l&15).
// LDS 48 KB (8 sXij + 8 sXcn + 32 sH). __launch_bounds__(256,2): 2 blocks/CU ->
// 8 waves/CU -> 2 waves/EU -> VGPR cap 256 (acc 64 + bq 64 fit, no spill).
// h_ij round-trips through hij_g (same block -> same XCD L2).
__global__ __launch_bounds__(256, 2) void mlp_k(const unsigned short* __restrict__ xij_g,
                                                const unsigned short* __restrict__ xcn_g,
                                                const unsigned short* __restrict__ WT,
                                                unsigned* __restrict__ hij_g,
                                                const float* __restrict__ xij_b1,
                                                const float* __restrict__ xij_b2,
                                                const float* __restrict__ xcn_b1,
                                                const float* __restrict__ xcn_b2,
                                                const float* __restrict__ xcn_b3,
                                                const float* __restrict__ lin_b1,
                                                const float* __restrict__ lin_w2,
                                                const float* __restrict__ lin_b2,
                                                const float* __restrict__ beta,
                                                float* __restrict__ out) {
    __shared__ unsigned short sXij[64 * 64];   // 8 KB, pre-swizzled (aliased as sRed later)
    __shared__ unsigned short sXcn[64 * 64];   // 8 KB, pre-swizzled
    __shared__ unsigned short sH[64 * 256];    // 32 KB activation (in-place reuse)

    const int tid  = threadIdx.x;
    const int wv   = tid >> 6;
    const int lane = tid & 63;
    const int lr   = lane & 15;
    const int lg   = lane >> 4;
    const int col0 = wv * 64;
    const int row0 = blockIdx.x * 64;
    const int boff = (col0 + lr) * 32 + 8 * lg;   // wave's B-slice offset within a tile

    // prologue: stage sXij (2 gll16) + sXcn (2 gll16), then preload B tiles 0..3
    // into the register rotation (16 loads). vmcnt(16) completes the 4 gll16s (FIFO).
    stage_act(xij_g + (size_t)row0 * FIN, sXij, tid, wv);
    stage_act(xcn_g + (size_t)row0 * FIN, sXcn, tid, wv);
    bf16x8 bq[4][4];
#pragma unroll
    for (int t = 0; t < 4; ++t)
#pragma unroll
        for (int n = 0; n < 4; ++n)
            bq[t][n] = *reinterpret_cast<const bf16x8*>(&WT[tile_off(t) + boff + n * 512]);
    const float betaf = beta[0];
    unsigned* hbase = hij_g + (size_t)(blockIdx.x * 4 + wv) * 2048 + lane * 2;
    asm volatile("s_waitcnt vmcnt(16)" ::: "memory");
    __builtin_amdgcn_s_barrier();

    f32x4 acc[4][4];
    float bl[4];

    // ---- P1 (t=0,1): h1 = relu(xij @ xij_w1 + b1) -> sH ----
    run_phase<0, 2, 64>(sXij, WT, boff, lr, lg, bq, acc);
#pragma unroll
    for (int n = 0; n < 4; ++n) bl[n] = xij_b1[col0 + n * 16 + lr];
#pragma unroll
    for (int m = 0; m < 4; ++m)
#pragma unroll
        for (int n = 0; n < 4; ++n)
#pragma unroll
            for (int i = 0; i < 4; ++i) {
                int row = m * 16 + 4 * lg + i;
                int col = col0 + n * 16 + lr;
                sH[row * HID + (col ^ ((row & 7) << 3))] = f2bf(fmaxf(acc[m][n][i] + bl[n], 0.f));
            }
    fence_barrier();   // B1: sH(h1) visible to all waves

    // ---- P2 (t=2..9): h_ij = h1 @ xij_w2 + b2 -> hij_g (L2-resident round-trip) ----
    run_phase<2, 8, 256>(sH, WT, boff, lr, lg, bq, acc);
#pragma unroll
    for (int n = 0; n < 4; ++n) bl[n] = xij_b2[col0 + n * 16 + lr];
#pragma unroll
    for (int m = 0; m < 4; ++m)
#pragma unroll
        for (int n = 0; n < 4; ++n) {
            uint2 v;
            v.x = ((unsigned)f2bf(acc[m][n][1] + bl[n]) << 16) | f2bf(acc[m][n][0] + bl[n]);
            v.y = ((unsigned)f2bf(acc[m][n][3] + bl[n]) << 16) | f2bf(acc[m][n][2] + bl[n]);
            *reinterpret_cast<uint2*>(hbase + (m * 4 + n) * 128) = v;
        }
    fence_barrier();   // B2: all waves' sH(h1) reads done; P3 epi may overwrite sH

    // ---- P3 (t=10,11): t1 = relu(xcn @ xcn_w1 + b1) -> sH ----
    run_phase<10, 2, 64>(sXcn, WT, boff, lr, lg, bq, acc);
#pragma unroll
    for (int n = 0; n < 4; ++n) bl[n] = xcn_b1[col0 + n * 16 + lr];
#pragma unroll
    for (int m = 0; m < 4; ++m)
#pragma unroll
        for (int n = 0; n < 4; ++n)
#pragma unroll
            for (int i = 0; i < 4; ++i) {
                int row = m * 16 + 4 * lg + i;
                int col = col0 + n * 16 + lr;
                sH[row * HID + (col ^ ((row & 7) << 3))] = f2bf(fmaxf(acc[m][n][i] + bl[n], 0.f));
            }
    fence_barrier();   // B3: sH(t1) visible

    // ---- P4 (t=12..19): t2 = relu(t1 @ xcn_w2 + b2) -> sH IN PLACE ----
    run_phase<12, 8, 256>(sH, WT, boff, lr, lg, bq, acc);
    fence_barrier();   // B4: all waves' t1 reads done before overwrite
#pragma unroll
    for (int n = 0; n < 4; ++n) bl[n] = xcn_b2[col0 + n * 16 + lr];
#pragma unroll
    for (int m = 0; m < 4; ++m)
#pragma unroll
        for (int n = 0; n < 4; ++n)
#pragma unroll
            for (int i = 0; i < 4; ++i) {
                int row = m * 16 + 4 * lg + i;
                int col = col0 + n * 16 + lr;
                sH[row * HID + (col ^ ((row & 7) << 3))] = f2bf(fmaxf(acc[m][n][i] + bl[n], 0.f));
            }
    fence_barrier();   // B5: sH(t2) visible

    // ---- P5 (t=20..27): u = (t2 @ xcn_w3 + b3) * beta + h_ij -> sH IN PLACE ----
    run_phase<20, 8, 256>(sH, WT, boff, lr, lg, bq, acc);
    fence_barrier();   // B6: all waves' t2 reads done
#pragma unroll
    for (int n = 0; n < 4; ++n) bl[n] = xcn_b3[col0 + n * 16 + lr];
#pragma unroll
    for (int m = 0; m < 4; ++m)
#pragma unroll
        for (int n = 0; n < 4; ++n) {
            uint2 v = *reinterpret_cast<const uint2*>(hbase + (m * 4 + n) * 128);
            float h0 = b2f((unsigned short)(v.x & 0xFFFF));
            float h1 = b2f((unsigned short)(v.x >> 16));
            float h2 = b2f((unsigned short)(v.y & 0xFFFF));
            float h3 = b2f((unsigned short)(v.y >> 16));
            float v0 = (acc[m][n][0] + bl[n]) * betaf + h0;
            float v1 = (acc[m][n][1] + bl[n]) * betaf + h1;
            float v2 = (acc[m][n][2] + bl[n]) * betaf + h2;
            float v3 = (acc[m][n][3] + bl[n]) * betaf + h3;
            int rb = m * 16 + 4 * lg;
            int col = col0 + n * 16 + lr;
            sH[(rb + 0) * HID + (col ^ (((rb + 0) & 7) << 3))] = f2bf(v0);
            sH[(rb + 1) * HID + (col ^ (((rb + 1) & 7) << 3))] = f2bf(v1);
            sH[(rb + 2) * HID + (col ^ (((rb + 2) & 7) << 3))] = f2bf(v2);
            sH[(rb + 3) * HID + (col ^ (((rb + 3) & 7) << 3))] = f2bf(v3);
        }
    fence_barrier();   // B7: sH(u) visible

    // ---- P6 (t=28..35): out = relu(u @ lin_w1 + lb1) . lin_w2 + lb2 ----
    run_phase<28, 8, 256>(sH, WT, boff, lr, lg, bq, acc);
#pragma unroll
    for (int n = 0; n < 4; ++n) bl[n] = lin_b1[col0 + n * 16 + lr];
    float w2l[4];
#pragma unroll
    for (int n = 0; n < 4; ++n) w2l[n] = lin_w2[col0 + n * 16 + lr];
    float* sRed = (float*)sXij;   // sXij dead since P1; 4 col-groups x 64 rows f32 (1 KB)
#pragma unroll
    for (int m = 0; m < 4; ++m) {
        float p[4] = {0.f, 0.f, 0.f, 0.f};
#pragma unroll
        for (int n = 0; n < 4; ++n)
#pragma unroll
            for (int i = 0; i < 4; ++i)
                p[i] += fmaxf(acc[m][n][i] + bl[n], 0.f) * w2l[n];
#pragma unroll
        for (int i = 0; i < 4; ++i) {
            float s = p[i];
            s += __shfl_xor(s, 1);
            s += __shfl_xor(s, 2);
            s += __shfl_xor(s, 4);
            s += __shfl_xor(s, 8);
            if (lr == 0) sRed[wv * 64 + m * 16 + 4 * lg + i] = s;
        }
    }
    __syncthreads();
    if (tid < 64)
        out[row0 + tid] = sRed[tid] + sRed[64 + tid] + sRed[128 + tid] + sRed[192 + tid] + lin_b2[0];
}

extern "C" void kernel_launch(void* const* d_in, const int* in_sizes, int n_in,
                              void* d_out, int out_size, void* d_ws, size_t ws_size,
                              hipStream_t stream) {
    const float* x      = (const float*)d_in[0];
    const int*   adj    = (const int*)d_in[1];
    const int*   tar    = (const int*)d_in[2];
    const float* beta   = (const float*)d_in[3];
    const float* xcn_w1 = (const float*)d_in[4];
    const float* xcn_b1 = (const float*)d_in[5];
    const float* xcn_w2 = (const float*)d_in[6];
    const float* xcn_b2 = (const float*)d_in[7];
    const float* xcn_w3 = (const float*)d_in[8];
    const float* xcn_b3 = (const float*)d_in[9];
    const float* xij_w1 = (const float*)d_in[10];
    const float* xij_b1 = (const float*)d_in[11];
    const float* xij_w2 = (const float*)d_in[12];
    const float* xij_b2 = (const float*)d_in[13];
    const float* lin_w1 = (const float*)d_in[14];
    const float* lin_b1 = (const float*)d_in[15];
    const float* lin_w2 = (const float*)d_in[16];
    const float* lin_b2 = (const float*)d_in[17];

    unsigned short* WT    = (unsigned short*)d_ws;                     // 576 KiB
    unsigned short* xij_g = (unsigned short*)((char*)d_ws + 589824);   // 4 MiB
    unsigned short* xcn_g = (unsigned short*)((char*)d_ws + 4784128);  // 4 MiB
    unsigned*       hij_g = (unsigned*)((char*)d_ws + 8978432);        // 16 MiB

    edge_prep_k<<<NEDGES / 4, 256, 0, stream>>>(x, adj, tar,
                                                xij_w1, xij_w2, xcn_w1, xcn_w2, xcn_w3, lin_w1,
                                                WT, xij_g, xcn_g);
    mlp_k<<<NEDGES / 64, 256, 0, stream>>>(xij_g, xcn_g, WT, hij_g,
                                           xij_b1, xij_b2, xcn_b1, xcn_b2, xcn_b3,
                                           lin_b1, lin_w2, lin_b2, beta, (float*)d_out);
}